// Round 1
// baseline (1681.158 us; speedup 1.0000x reference)
//
#include <hip/hip_runtime.h>
#include <hip/hip_cooperative_groups.h>
#include <stdint.h>

namespace cg = cooperative_groups;

#define FPOFF _Pragma("clang fp contract(off)")

// ---------------- problem sizes ----------------
#define ROWS 8192      // N*Ho*Wo = 8*32*32
#define OC 128
#define NS 5           // subarrays
#define SUB 128
#define LP 640         // NS*SUB (padded L)
#define LREAL 576      // C*kh*kw = 64*9
#define NZ 7           // activation bits
#define NK 3           // weight cells
#define NSLOT 21
#define NPTOT 245760   // 3*128*5*128   probs element count
#define NNTOT 1720320  // 7*3*128*5*128 noise element count

// ---------------- ws layout (bytes) ----------------
#define OFF_HDR      0u          // u32[64]: [0]=xmax_enc, pmin[21]@idx8, pmax[21]@idx32
#define OFF_WSCALE   256u        // f32 [NS][OC]
#define OFF_WQ       4096u       // i8  [OC][LP]
#define OFF_CLS      86016u      // u8  [NK][OC][NS][SUB]
#define OFF_INPUTQ   331776u     // u8  [ROWS][LP]
#define OFF_PACKB    5574656u    // u32 [NZ][ROWS][NS][4]
#define OFF_RQ       10162176u   // f32 [NZ][NK][NS][SUB][OC]  (ends ~17.0 MB)

struct U2 { uint32_t x, y; };

__host__ __device__ static inline uint32_t rotl32(uint32_t v, int d){ return (v << d) | (v >> (32 - d)); }

// JAX threefry2x32: 20 rounds, injection every 4. keys (k0,k1), counter (c0,c1).
__host__ __device__ static inline U2 threefry(uint32_t k0, uint32_t k1, uint32_t c0, uint32_t c1){
  uint32_t ks2 = k0 ^ k1 ^ 0x1BD11BDAu;
  uint32_t x0 = c0 + k0, x1 = c1 + k1;
#define TFR(r) { x0 += x1; x1 = rotl32(x1, r); x1 ^= x0; }
  TFR(13) TFR(15) TFR(26) TFR(6)  x0 += k1;  x1 += ks2 + 1u;
  TFR(17) TFR(29) TFR(16) TFR(24) x0 += ks2; x1 += k0 + 2u;
  TFR(13) TFR(15) TFR(26) TFR(6)  x0 += k0;  x1 += k1 + 3u;
  TFR(17) TFR(29) TFR(16) TFR(24) x0 += k1;  x1 += ks2 + 4u;
  TFR(13) TFR(15) TFR(26) TFR(6)  x0 += ks2; x1 += k0 + 5u;
#undef TFR
  U2 r; r.x = x0; r.y = x1; return r;
}

__device__ static inline float u2f(uint32_t b){
  // JAX uniform [0,1): bitcast((bits>>9)|0x3f800000) - 1
  return __uint_as_float((b >> 9) | 0x3F800000u) - 1.0f;
}

// order-preserving float<->uint encode for atomic min/max
__device__ static inline uint32_t encf(float f){
  uint32_t u = __float_as_uint(f);
  return (u & 0x80000000u) ? ~u : (u | 0x80000000u);
}
__device__ static inline float decf(uint32_t e){
  return (e & 0x80000000u) ? __uint_as_float(e & 0x7FFFFFFFu) : __uint_as_float(~e);
}

// XLA/chlo erf_inv f32 (Giles). log1p/sqrt via f64 for correctly-rounded f32.
__device__ static inline float xla_erfinv(float x){
  FPOFF
  float m = x * x;
  float w = -(float)log1p((double)(-m));
  float p;
  if (w < 5.0f){
    w = w - 2.5f;
    p = 2.81022636e-08f;
    p = 3.43273939e-07f  + p * w;
    p = -3.5233877e-06f  + p * w;
    p = -4.39150654e-06f + p * w;
    p = 0.00021858087f   + p * w;
    p = -0.00125372503f  + p * w;
    p = -0.00417768164f  + p * w;
    p = 0.246640727f     + p * w;
    p = 1.50140941f      + p * w;
  } else {
    w = (float)sqrt((double)w) - 3.0f;
    p = -0.000200214257f;
    p = 0.000100950558f  + p * w;
    p = 0.00134934322f   + p * w;
    p = -0.00367342844f  + p * w;
    p = 0.00573950773f   + p * w;
    p = -0.0076224613f   + p * w;
    p = 0.00943887047f   + p * w;
    p = 1.00167406f      + p * w;
    p = 2.83297682f      + p * w;
  }
  return p * x;
}

// ---------------- kernels ----------------

__global__ void k_init(uint32_t* hdr){
  int t = threadIdx.x;
  if (t == 0) hdr[0] = 0u;
  if (t < NSLOT){ hdr[8 + t] = 0xFFFFFFFFu; hdr[32 + t] = 0u; }
}

// two-stage max: per-thread 16 elems -> wave shuffle -> LDS -> 1 atomic/block
__global__ void k_xmax(const float* __restrict__ x, uint32_t* hdr){
  __shared__ float red[4];
  int t = threadIdx.x;
  const float4* x4 = (const float4*)x;
  int base = blockIdx.x * 1024 + t;     // 128 blocks * 1024 float4 = 524288 floats
  float m = 0.0f;                        // x >= 0 (uniform[0,1))
#pragma unroll
  for (int i = 0; i < 4; ++i){
    float4 v = x4[base + i * 256];
    m = fmaxf(m, fmaxf(fmaxf(v.x, v.y), fmaxf(v.z, v.w)));
  }
  for (int off = 32; off; off >>= 1) m = fmaxf(m, __shfl_down(m, off));
  if ((t & 63) == 0) red[t >> 6] = m;
  __syncthreads();
  if (t == 0){
    m = fmaxf(fmaxf(red[0], red[1]), fmaxf(red[2], red[3]));
    atomicMax(&hdr[0], encf(m));
  }
}

// per (s,o): w_scale = max(|w|,1e-8)/127 ; wq = rint(w/w_scale) as i8
__global__ void k_wq(const float* __restrict__ wt, float* __restrict__ wscale, int8_t* __restrict__ wq){
  FPOFF
  int s = blockIdx.x, o = blockIdx.y, t = threadIdx.x;  // 64 threads
  int l0 = s * SUB + t, l1 = l0 + 64;
  float w0 = (l0 < LREAL) ? wt[o * LREAL + l0] : 0.f;
  float w1 = (l1 < LREAL) ? wt[o * LREAL + l1] : 0.f;
  float m = fmaxf(fabsf(w0), fabsf(w1));
  for (int off = 32; off; off >>= 1) m = fmaxf(m, __shfl_down(m, off));
  m = __shfl(m, 0);
  float ws = fmaxf(m, 1e-8f) / 127.0f;
  if (t == 0) wscale[s * OC + o] = ws;
  wq[o * LP + l0] = (int8_t)(int)rintf(w0 / ws);
  wq[o * LP + l1] = (int8_t)(int)rintf(w1 / ws);
}

// im2col + per-tensor activation quant to u8
__global__ void k_inputq(const float* __restrict__ x, const uint32_t* __restrict__ hdr, uint8_t* __restrict__ iq){
  FPOFF
  int r = blockIdx.x, t = threadIdx.x;
  float a_scale = fmaxf(decf(hdr[0]), 1e-8f) / 127.0f;
  int n = r >> 10, hw = r & 1023, oh = hw >> 5, ow = hw & 31;
  for (int l = t; l < LP; l += 256){
    float val = 0.f;
    if (l < LREAL){
      int c = l / 9, r9 = l - c * 9, ki = r9 / 3, kj = r9 - ki * 3;
      int ih = oh - 1 + ki, iw = ow - 1 + kj;
      if ((unsigned)ih < 32u && (unsigned)iw < 32u)
        val = x[(((n << 6) + c) << 10) + (ih << 5) + iw];
    }
    iq[r * LP + l] = (uint8_t)(int)rintf(val / a_scale);
  }
}

// pack bit z of inputQ into u32 words: packB[z][r][s][w], bit t = j = w*32+t
__global__ void k_pack(const uint8_t* __restrict__ iq, uint32_t* __restrict__ packB){
  int gid = blockIdx.x * 256 + threadIdx.x;
  if (gid >= ROWS * 20) return;
  int r = gid / 20, sw = gid - r * 20;
  const uint4* p4 = (const uint4*)(iq + r * LP + sw * 32);
  uint4 a = p4[0], b2 = p4[1];
  uint32_t wds[8] = {a.x, a.y, a.z, a.w, b2.x, b2.y, b2.z, b2.w};
  uint32_t out[NZ];
#pragma unroll
  for (int z = 0; z < NZ; ++z) out[z] = 0u;
#pragma unroll
  for (int tt = 0; tt < 32; ++tt){
    uint32_t byte = (wds[tt >> 2] >> ((tt & 3) * 8)) & 0xFFu;
#pragma unroll
    for (int z = 0; z < NZ; ++z) out[z] |= ((byte >> z) & 1u) << tt;
  }
#pragma unroll
  for (int z = 0; z < NZ; ++z) packB[(z * ROWS + r) * 20 + sw] = out[z];
}

// SAF classes from uniform(kmask): 0 normal / 1 sa0 / 2 sa1
__global__ void k_cls(uint8_t* __restrict__ cls, uint32_t km0, uint32_t km1){
  int i = blockIdx.x * 256 + threadIdx.x;
  if (i >= NPTOT) return;
  U2 r = threefry(km0, km1, 0u, (uint32_t)i);
  float f = u2f(r.x ^ r.y);
  cls[i] = (f < 0.001f) ? 1 : ((f > 0.999f) ? 2 : 0);
}

// rQ[z][k][s][j][o] = SAF(where(sa)) of rem*(1+noise)
__global__ void k_rq(const int8_t* __restrict__ wq, const uint8_t* __restrict__ cls,
                     float* __restrict__ rq, uint32_t kn0, uint32_t kn1){
  FPOFF
  int i = blockIdx.x * 256 + threadIdx.x;
  if (i >= NNTOT) return;
  U2 rr = threefry(kn0, kn1, 0u, (uint32_t)i);
  uint32_t bits = rr.x ^ rr.y;
  // noise flat index [z][k][o][s][j]
  int j = i & 127;
  int t = i >> 7;
  int s = t % 5;
  int t2 = t / 5;
  int o = t2 & 127;
  int t3 = t2 >> 7;
  int k = t3 % 3;
  int z = t3 / 3;
  float f = u2f(bits);
  float u = fmaxf(-0x1.fffffep-1f, f * 2.0f + (-0x1.fffffep-1f));
  float nv = (0x1.6a09e6p+0f * xla_erfinv(u)) * 0.05f;
  int wv = (int)wq[o * LP + s * SUB + j];
  int r0 = wv % 4;  int x1 = (wv - r0) / 4;
  int r1 = x1 % 4;  int x2 = (x1 - r1) / 4;
  int r2 = x2 % 4;
  int rem = (k == 0) ? r0 : ((k == 1) ? r1 : r2);
  float remf = (float)rem;
  float v = remf + remf * nv;
  int c = cls[((k * OC + o) * NS + s) * SUB + j];
  if (c == 1) v = 0.1f;
  else if (c == 2) v = (v > 0.f) ? 1.f : ((v < 0.f) ? -1.f : 0.f);
  rq[(((z * NK + k) * NS + s) * SUB + j) * OC + o] = v;
}

// ---------------- fused z/k loop: one cooperative kernel ----------------
// grid (128,4) x 256 threads = 512 blocks = 2 blocks/CU (guaranteed by
// __launch_bounds__(256,2)).  Thread owns (row = bx*64+lane,
// o-tile = by*32 + wave*8 .. +7) for ALL 5 subarrays:
//   acc[5][8] registers  -> per-slot global min/max (block atomics) ->
//   grid.sync() -> quantize from registers -> outD/outacc registers.
// Eliminates partial[] (882 MB round-trip) + outD/outacc traffic + 41 launches.
// Per-element arithmetic order identical to the split version (bit-exact).
__global__ __launch_bounds__(256, 2) void k_fused(
    const float* __restrict__ rq, const uint32_t* __restrict__ packB,
    const float* __restrict__ wscale, uint32_t* __restrict__ hdr,
    const float* __restrict__ bias, float* __restrict__ out)
{
  FPOFF
  cg::grid_group grid = cg::this_grid();
  __shared__ float red[8];
  const int tid  = threadIdx.x;
  const int wave = tid >> 6;
  const int lane = tid & 63;
  const int r    = blockIdx.x * 64 + lane;
  const int o0   = __builtin_amdgcn_readfirstlane(blockIdx.y * 32 + wave * 8);

  const float a_scale = fmaxf(decf(hdr[0]), 1e-8f) / 127.0f;

  float outD_[8], outacc_[8];
#pragma unroll
  for (int i = 0; i < 8; ++i){ outD_[i] = 0.f; outacc_[i] = 0.f; }

#pragma unroll 1
  for (int z = 0; z < NZ; ++z){
    // bit words for this z, all 5 subarrays (shared across the 3 k's)
    uint4 bwv[NS];
#pragma unroll
    for (int s = 0; s < NS; ++s)
      bwv[s] = *(const uint4*)(packB + ((size_t)z * ROWS + r) * 20 + s * 4);

#pragma unroll 1
    for (int k = 0; k < NK; ++k){
      const int slot = z * NK + k;
      const float* rqs = rq + (size_t)slot * (NS * SUB * OC);

      float acc[NS][8];
#pragma unroll
      for (int s = 0; s < NS; ++s)
#pragma unroll
        for (int i = 0; i < 8; ++i) acc[s][i] = 0.f;

      // ---- mm phase: acc[s][i] = sum_j bit * rq, j ascending (bit-exact) ----
#pragma unroll
      for (int s = 0; s < NS; ++s){
        const float* rvbase = rqs + s * SUB * OC + o0;   // wave-uniform -> s_load
        const uint32_t bw0 = bwv[s].x, bw1 = bwv[s].y, bw2 = bwv[s].z, bw3 = bwv[s].w;
        const uint32_t bwarr[4] = {bw0, bw1, bw2, bw3};
#pragma unroll
        for (int w = 0; w < 4; ++w){
#pragma unroll 1
          for (int jb = 0; jb < 32; jb += 8){
            uint32_t wrd = bwarr[w] >> jb;               // uniform shift amount
            const float* p0 = rvbase + (w * 32 + jb) * OC;
#pragma unroll
            for (int u = 0; u < 8; ++u){
              float bitf = (float)((wrd >> u) & 1u);     // bfe + cvt: exactly 0.0/1.0
              const float* p = p0 + u * OC;
#pragma unroll
              for (int i = 0; i < 8; ++i)
                acc[s][i] = __builtin_fmaf(p[i], bitf, acc[s][i]);
            }
          }
        }
      }

      // ---- global min/max over the slot's 5*8192*128 values ----
      float mn = acc[0][0], mx = acc[0][0];
#pragma unroll
      for (int s = 0; s < NS; ++s)
#pragma unroll
        for (int i = 0; i < 8; ++i){ mn = fminf(mn, acc[s][i]); mx = fmaxf(mx, acc[s][i]); }
      for (int off = 32; off; off >>= 1){
        mn = fminf(mn, __shfl_down(mn, off));
        mx = fmaxf(mx, __shfl_down(mx, off));
      }
      if (lane == 0){ red[wave] = mn; red[4 + wave] = mx; }
      __syncthreads();
      if (tid == 0){
        mn = fminf(fminf(red[0], red[1]), fminf(red[2], red[3]));
        mx = fmaxf(fmaxf(red[4], red[5]), fmaxf(red[6], red[7]));
        atomicMin(&hdr[8 + slot], encf(mn));
        atomicMax(&hdr[32 + slot], encf(mx));
      }
      grid.sync();

      // device-scope coherent read of the reduced min/max (XCD L2 non-coherent
      // for plain loads); one reader per block, LDS broadcast.
      if (tid == 0){
        uint32_t emn = __hip_atomic_load(&hdr[8 + slot],  __ATOMIC_RELAXED, __HIP_MEMORY_SCOPE_AGENT);
        uint32_t emx = __hip_atomic_load(&hdr[32 + slot], __ATOMIC_RELAXED, __HIP_MEMORY_SCOPE_AGENT);
        red[0] = decf(emn);
        red[1] = decf(emx);
      }
      __syncthreads();
      mn = red[0];
      const float mxv = red[1];

      float step = (mxv - mn) * 0.03125f;
      if (!(step > 0.f)) step = 1.0f;

      // ---- quant + s-sum + z/k accumulation (identical op order to k_quant) ----
#pragma unroll
      for (int i = 0; i < 8; ++i){
        float pq = 0.f;
#pragma unroll
        for (int s = 0; s < NS; ++s){
          float v = acc[s][i];
          float fidx = floorf((v - mn) / step);
          fidx = fminf(fmaxf(fidx, 0.f), 31.f);
          float qv = fidx * step + mn;
          pq = pq + qv * wscale[s * OC + o0 + i];
        }
        if (k == 0) outD_[i] = pq;
        else if (k == 1) outD_[i] = outD_[i] + pq * 4.0f;
        else {
          float tt = outD_[i] + pq * 16.0f;
          float contrib = (tt * (float)(1 << z)) * a_scale;
          if (z == 0) outacc_[i] = contrib;
          else if (z < NZ - 1) outacc_[i] = outacc_[i] + contrib;
          else {
            int n = r >> 10, hw = r & 1023;
            out[(((n << 7) + (o0 + i)) << 10) + hw] = outacc_[i] + contrib + bias[o0 + i];
          }
        }
      }
      __syncthreads();   // protect red[] WAR before next slot's reduction writes
    }
  }
}

// ---------------- host ----------------
extern "C" void kernel_launch(void* const* d_in, const int* in_sizes, int n_in,
                              void* d_out, int out_size, void* d_ws, size_t ws_size,
                              hipStream_t stream){
  const float* x    = (const float*)d_in[0];
  const float* wt   = (const float*)d_in[1];
  const float* bias = (const float*)d_in[2];
  float* out = (float*)d_out;
  char* ws = (char*)d_ws;
  uint32_t* hdr    = (uint32_t*)(ws + OFF_HDR);
  float*    wscale = (float*)(ws + OFF_WSCALE);
  int8_t*   wq     = (int8_t*)(ws + OFF_WQ);
  uint8_t*  cls    = (uint8_t*)(ws + OFF_CLS);
  uint8_t*  iq     = (uint8_t*)(ws + OFF_INPUTQ);
  uint32_t* packB  = (uint32_t*)(ws + OFF_PACKB);
  float*    rq     = (float*)(ws + OFF_RQ);

  // jax.random.key(42) -> (0,42); partitionable split:
  // kmask = threefry(key,(0,0)); knoise = threefry(key,(0,1))
  U2 p0 = threefry(0u, 42u, 0u, 0u);
  U2 p1 = threefry(0u, 42u, 0u, 1u);

  hipLaunchKernelGGL(k_init,   dim3(1),           dim3(64),  0, stream, hdr);
  hipLaunchKernelGGL(k_xmax,   dim3(128),         dim3(256), 0, stream, x, hdr);
  hipLaunchKernelGGL(k_wq,     dim3(5, 128),      dim3(64),  0, stream, wt, wscale, wq);
  hipLaunchKernelGGL(k_inputq, dim3(8192),        dim3(256), 0, stream, x, hdr, iq);
  hipLaunchKernelGGL(k_pack,   dim3(640),         dim3(256), 0, stream, iq, packB);
  hipLaunchKernelGGL(k_cls,    dim3(NPTOT / 256), dim3(256), 0, stream, cls, p0.x, p0.y);
  hipLaunchKernelGGL(k_rq,     dim3(NNTOT / 256), dim3(256), 0, stream, wq, cls, rq, p1.x, p1.y);

  const float*    rq_c     = rq;
  const uint32_t* packB_c  = packB;
  const float*    wscale_c = wscale;
  uint32_t*       hdr_c    = hdr;
  const float*    bias_c   = bias;
  float*          out_c    = out;
  void* kargs[] = { (void*)&rq_c, (void*)&packB_c, (void*)&wscale_c,
                    (void*)&hdr_c, (void*)&bias_c, (void*)&out_c };
  hipLaunchCooperativeKernel((void*)k_fused, dim3(128, 4), dim3(256), kargs, 0, stream);
}

// Round 4
// 1555.389 us; speedup vs baseline: 1.0809x; 1.0809x over previous
//
#include <hip/hip_runtime.h>
#include <stdint.h>

#define FPOFF _Pragma("clang fp contract(off)")

// ---------------- problem sizes ----------------
#define ROWS 8192      // N*Ho*Wo = 8*32*32
#define OC 128
#define NS 5           // subarrays
#define SUB 128
#define LP 640         // NS*SUB (padded L)
#define LREAL 576      // C*kh*kw = 64*9
#define NZ 7           // activation bits
#define NK 3           // weight cells
#define NSLOT 21
#define NPTOT 245760   // 3*128*5*128   probs element count
#define NNTOT 1720320  // 7*3*128*5*128 noise element count

// ---------------- ws layout (bytes) ----------------
#define OFF_HDR      0u          // u32[64]: [0]=xmax_enc, pmin[21]@idx8, pmax[21]@idx32
#define OFF_WSCALE   256u        // f32 [NS][OC]
#define OFF_WQ       4096u       // i8  [OC][LP]
#define OFF_CLS      86016u      // u8  [NK][OC][NS][SUB]
#define OFF_INPUTQ   331776u     // u8  [ROWS][LP]
#define OFF_PACKB    5574656u    // u32 [NZ][ROWS][NS][4]
#define OFF_RQ       10162176u   // f32 [NZ][NK][NS][SUB][OC]
#define OFF_PARTIAL  17043456u   // f32 [NS][ROWS][OC]
#define OFF_OUTD     38014976u   // f32 [ROWS][OC]
#define OFF_OUTACC   42209280u   // f32 [ROWS][OC]  (total ~46.4 MB)

struct U2 { uint32_t x, y; };

__host__ __device__ static inline uint32_t rotl32(uint32_t v, int d){ return (v << d) | (v >> (32 - d)); }

// JAX threefry2x32: 20 rounds, injection every 4. keys (k0,k1), counter (c0,c1).
__host__ __device__ static inline U2 threefry(uint32_t k0, uint32_t k1, uint32_t c0, uint32_t c1){
  uint32_t ks2 = k0 ^ k1 ^ 0x1BD11BDAu;
  uint32_t x0 = c0 + k0, x1 = c1 + k1;
#define TFR(r) { x0 += x1; x1 = rotl32(x1, r); x1 ^= x0; }
  TFR(13) TFR(15) TFR(26) TFR(6)  x0 += k1;  x1 += ks2 + 1u;
  TFR(17) TFR(29) TFR(16) TFR(24) x0 += ks2; x1 += k0 + 2u;
  TFR(13) TFR(15) TFR(26) TFR(6)  x0 += k0;  x1 += k1 + 3u;
  TFR(17) TFR(29) TFR(16) TFR(24) x0 += k1;  x1 += ks2 + 4u;
  TFR(13) TFR(15) TFR(26) TFR(6)  x0 += ks2; x1 += k0 + 5u;
#undef TFR
  U2 r; r.x = x0; r.y = x1; return r;
}

__device__ static inline float u2f(uint32_t b){
  // JAX uniform [0,1): bitcast((bits>>9)|0x3f800000) - 1
  return __uint_as_float((b >> 9) | 0x3F800000u) - 1.0f;
}

// order-preserving float<->uint encode for atomic min/max
__device__ static inline uint32_t encf(float f){
  uint32_t u = __float_as_uint(f);
  return (u & 0x80000000u) ? ~u : (u | 0x80000000u);
}
__device__ static inline float decf(uint32_t e){
  return (e & 0x80000000u) ? __uint_as_float(e & 0x7FFFFFFFu) : __uint_as_float(~e);
}

// XLA/chlo erf_inv f32 (Giles). log1p/sqrt via f64 for correctly-rounded f32.
__device__ static inline float xla_erfinv(float x){
  FPOFF
  float m = x * x;
  float w = -(float)log1p((double)(-m));
  float p;
  if (w < 5.0f){
    w = w - 2.5f;
    p = 2.81022636e-08f;
    p = 3.43273939e-07f  + p * w;
    p = -3.5233877e-06f  + p * w;
    p = -4.39150654e-06f + p * w;
    p = 0.00021858087f   + p * w;
    p = -0.00125372503f  + p * w;
    p = -0.00417768164f  + p * w;
    p = 0.246640727f     + p * w;
    p = 1.50140941f      + p * w;
  } else {
    w = (float)sqrt((double)w) - 3.0f;
    p = -0.000200214257f;
    p = 0.000100950558f  + p * w;
    p = 0.00134934322f   + p * w;
    p = -0.00367342844f  + p * w;
    p = 0.00573950773f   + p * w;
    p = -0.0076224613f   + p * w;
    p = 0.00943887047f   + p * w;
    p = 1.00167406f      + p * w;
    p = 2.83297682f      + p * w;
  }
  return p * x;
}

// ---------------- kernels ----------------

__global__ void k_init(uint32_t* hdr){
  int t = threadIdx.x;
  if (t == 0) hdr[0] = 0u;
  if (t < NSLOT){ hdr[8 + t] = 0xFFFFFFFFu; hdr[32 + t] = 0u; }
}

// two-stage max: per-thread 16 elems -> wave shuffle -> LDS -> 1 atomic/block
__global__ void k_xmax(const float* __restrict__ x, uint32_t* hdr){
  __shared__ float red[4];
  int t = threadIdx.x;
  const float4* x4 = (const float4*)x;
  int base = blockIdx.x * 1024 + t;     // 128 blocks * 1024 float4 = 524288 floats
  float m = 0.0f;                        // x >= 0 (uniform[0,1))
#pragma unroll
  for (int i = 0; i < 4; ++i){
    float4 v = x4[base + i * 256];
    m = fmaxf(m, fmaxf(fmaxf(v.x, v.y), fmaxf(v.z, v.w)));
  }
  for (int off = 32; off; off >>= 1) m = fmaxf(m, __shfl_down(m, off));
  if ((t & 63) == 0) red[t >> 6] = m;
  __syncthreads();
  if (t == 0){
    m = fmaxf(fmaxf(red[0], red[1]), fmaxf(red[2], red[3]));
    atomicMax(&hdr[0], encf(m));
  }
}

// per (s,o): w_scale = max(|w|,1e-8)/127 ; wq = rint(w/w_scale) as i8
__global__ void k_wq(const float* __restrict__ wt, float* __restrict__ wscale, int8_t* __restrict__ wq){
  FPOFF
  int s = blockIdx.x, o = blockIdx.y, t = threadIdx.x;  // 64 threads
  int l0 = s * SUB + t, l1 = l0 + 64;
  float w0 = (l0 < LREAL) ? wt[o * LREAL + l0] : 0.f;
  float w1 = (l1 < LREAL) ? wt[o * LREAL + l1] : 0.f;
  float m = fmaxf(fabsf(w0), fabsf(w1));
  for (int off = 32; off; off >>= 1) m = fmaxf(m, __shfl_down(m, off));
  m = __shfl(m, 0);
  float ws = fmaxf(m, 1e-8f) / 127.0f;
  if (t == 0) wscale[s * OC + o] = ws;
  wq[o * LP + l0] = (int8_t)(int)rintf(w0 / ws);
  wq[o * LP + l1] = (int8_t)(int)rintf(w1 / ws);
}

// im2col + per-tensor activation quant to u8
__global__ void k_inputq(const float* __restrict__ x, const uint32_t* __restrict__ hdr, uint8_t* __restrict__ iq){
  FPOFF
  int r = blockIdx.x, t = threadIdx.x;
  float a_scale = fmaxf(decf(hdr[0]), 1e-8f) / 127.0f;
  int n = r >> 10, hw = r & 1023, oh = hw >> 5, ow = hw & 31;
  for (int l = t; l < LP; l += 256){
    float val = 0.f;
    if (l < LREAL){
      int c = l / 9, r9 = l - c * 9, ki = r9 / 3, kj = r9 - ki * 3;
      int ih = oh - 1 + ki, iw = ow - 1 + kj;
      if ((unsigned)ih < 32u && (unsigned)iw < 32u)
        val = x[(((n << 6) + c) << 10) + (ih << 5) + iw];
    }
    iq[r * LP + l] = (uint8_t)(int)rintf(val / a_scale);
  }
}

// pack bit z of inputQ into u32 words: packB[z][r][s][w], bit t = j = w*32+t
__global__ void k_pack(const uint8_t* __restrict__ iq, uint32_t* __restrict__ packB){
  int gid = blockIdx.x * 256 + threadIdx.x;
  if (gid >= ROWS * 20) return;
  int r = gid / 20, sw = gid - r * 20;
  const uint4* p4 = (const uint4*)(iq + r * LP + sw * 32);
  uint4 a = p4[0], b2 = p4[1];
  uint32_t wds[8] = {a.x, a.y, a.z, a.w, b2.x, b2.y, b2.z, b2.w};
  uint32_t out[NZ];
#pragma unroll
  for (int z = 0; z < NZ; ++z) out[z] = 0u;
#pragma unroll
  for (int tt = 0; tt < 32; ++tt){
    uint32_t byte = (wds[tt >> 2] >> ((tt & 3) * 8)) & 0xFFu;
#pragma unroll
    for (int z = 0; z < NZ; ++z) out[z] |= ((byte >> z) & 1u) << tt;
  }
#pragma unroll
  for (int z = 0; z < NZ; ++z) packB[(z * ROWS + r) * 20 + sw] = out[z];
}

// SAF classes from uniform(kmask): 0 normal / 1 sa0 / 2 sa1
__global__ void k_cls(uint8_t* __restrict__ cls, uint32_t km0, uint32_t km1){
  int i = blockIdx.x * 256 + threadIdx.x;
  if (i >= NPTOT) return;
  U2 r = threefry(km0, km1, 0u, (uint32_t)i);
  float f = u2f(r.x ^ r.y);
  cls[i] = (f < 0.001f) ? 1 : ((f > 0.999f) ? 2 : 0);
}

// rQ[z][k][s][j][o] = SAF(where(sa)) of rem*(1+noise) — EXACT round-0 layout
__global__ void k_rq(const int8_t* __restrict__ wq, const uint8_t* __restrict__ cls,
                     float* __restrict__ rq, uint32_t kn0, uint32_t kn1){
  FPOFF
  int i = blockIdx.x * 256 + threadIdx.x;
  if (i >= NNTOT) return;
  U2 rr = threefry(kn0, kn1, 0u, (uint32_t)i);
  uint32_t bits = rr.x ^ rr.y;
  // noise flat index [z][k][o][s][j]
  int j = i & 127;
  int t = i >> 7;
  int s = t % 5;
  int t2 = t / 5;
  int o = t2 & 127;
  int t3 = t2 >> 7;
  int k = t3 % 3;
  int z = t3 / 3;
  float f = u2f(bits);
  float u = fmaxf(-0x1.fffffep-1f, f * 2.0f + (-0x1.fffffep-1f));
  float nv = (0x1.6a09e6p+0f * xla_erfinv(u)) * 0.05f;
  int wv = (int)wq[o * LP + s * SUB + j];
  int r0 = wv % 4;  int x1 = (wv - r0) / 4;
  int r1 = x1 % 4;  int x2 = (x1 - r1) / 4;
  int r2 = x2 % 4;
  int rem = (k == 0) ? r0 : ((k == 1) ? r1 : r2);
  float remf = (float)rem;
  float v = remf + remf * nv;
  int c = cls[((k * OC + o) * NS + s) * SUB + j];
  if (c == 1) v = 0.1f;
  else if (c == 2) v = (v > 0.f) ? 1.f : ((v < 0.f) ? -1.f : 0.f);
  rq[(((z * NK + k) * NS + s) * SUB + j) * OC + o] = v;
}

// partial[s][r][o] = sum_j bit(r,j) * rQ[j][o], j=0..127 strictly ascending
// (bit-exact vs reference).  NEW mapping vs round 0: lane = o so rq comes in
// as one coalesced global_load_dword per j (L2-resident slice, latency hidden
// by multiple waves); 16 rows per wave are WAVE-UNIFORM so their bit words sit
// in SGPRs and bit->{0.0f,1.0f} is SALU (s_bitcmp+s_cselect), leaving the VALU
// stream as pure v_fmac v_acc, s_fb, v_rq.  Same grid dims as round 0.
__global__ __launch_bounds__(256) void k_mm(const float* __restrict__ rq_slice,
                                            const uint32_t* __restrict__ packB_z,
                                            float* __restrict__ partial,
                                            uint32_t* __restrict__ hdr, int slot){
  FPOFF
  __shared__ float red[8];
  const int tid  = threadIdx.x;
  const int wave = tid >> 6;
  const int lane = tid & 63;
  const int s    = blockIdx.z;
  const int o    = blockIdx.y * 64 + lane;
  const int rbase = __builtin_amdgcn_readfirstlane(blockIdx.x * 64 + wave * 16);

  const float* rqs = rq_slice + (size_t)s * SUB * OC + o;   // per-lane column base

  float acc[16];
#pragma unroll
  for (int rr = 0; rr < 16; ++rr) acc[rr] = 0.f;

#pragma unroll 1
  for (int w = 0; w < 4; ++w){
    uint32_t wd[16];
#pragma unroll
    for (int rr = 0; rr < 16; ++rr)
      wd[rr] = packB_z[(size_t)(rbase + rr) * 20 + s * 4 + w];  // uniform -> s_load
#pragma unroll
    for (int jj = 0; jj < 32; ++jj){
      const float v = rqs[(size_t)(w * 32 + jj) * OC];          // coalesced dword
#pragma unroll
      for (int rr = 0; rr < 16; ++rr){
        const float fb = ((wd[rr] >> jj) & 1u) ? 1.0f : 0.0f;   // SALU select
        acc[rr] = __builtin_fmaf(v, fb, acc[rr]);               // j ascending chain
      }
    }
  }

  // store partial[s][r][o]: o = lane -> 256B contiguous per wave per rr
#pragma unroll
  for (int rr = 0; rr < 16; ++rr)
    partial[((size_t)s * ROWS + (rbase + rr)) * OC + o] = acc[rr];

  // block min/max (64 rows x 64 o x 1 s) -> slot atomics (exact, order-free)
  float mn = acc[0], mx = acc[0];
#pragma unroll
  for (int rr = 1; rr < 16; ++rr){ mn = fminf(mn, acc[rr]); mx = fmaxf(mx, acc[rr]); }
  for (int off = 32; off; off >>= 1){
    mn = fminf(mn, __shfl_down(mn, off));
    mx = fmaxf(mx, __shfl_down(mx, off));
  }
  if (lane == 0){ red[wave] = mn; red[4 + wave] = mx; }
  __syncthreads();
  if (tid == 0){
    mn = fminf(fminf(red[0], red[1]), fminf(red[2], red[3]));
    mx = fmaxf(fmaxf(red[4], red[5]), fmaxf(red[6], red[7]));
    atomicMin(&hdr[8 + slot], encf(mn));
    atomicMax(&hdr[32 + slot], encf(mx));
  }
}

// ADC quant + ws_T scale + subarray sum + z/k accumulation (reference order)
__global__ void k_quant(const float* __restrict__ partial, const float* __restrict__ wscale,
                        const uint32_t* __restrict__ hdr, float* __restrict__ outD,
                        float* __restrict__ outacc, float* __restrict__ out,
                        const float* __restrict__ bias, int z, int k, int slot){
  FPOFF
  int e = blockIdx.x * 256 + threadIdx.x;   // exactly ROWS*OC threads
  int r = e >> 7, o = e & 127;
  float mn = decf(hdr[8 + slot]);
  float mx = decf(hdr[32 + slot]);
  float delta = mx - mn;
  float step = delta * 0.03125f;
  if (!(step > 0.f)) step = 1.0f;
  float pq = 0.f;
#pragma unroll
  for (int s = 0; s < NS; ++s){
    float v = partial[(size_t)(s * ROWS + r) * OC + o];
    float fidx = floorf((v - mn) / step);
    fidx = fminf(fmaxf(fidx, 0.f), 31.f);
    float qv = fidx * step + mn;
    pq = pq + qv * wscale[s * OC + o];
  }
  if (k == 0) outD[e] = pq;
  else if (k == 1) outD[e] = outD[e] + pq * 4.0f;
  else {
    float tt = outD[e] + pq * 16.0f;
    float a_scale = fmaxf(decf(hdr[0]), 1e-8f) / 127.0f;
    float contrib = (tt * (float)(1 << z)) * a_scale;
    if (z == 0) outacc[e] = contrib;
    else if (z < 6) outacc[e] = outacc[e] + contrib;
    else {
      float res = outacc[e] + contrib;
      int n = r >> 10, hw = r & 1023;
      out[(((n << 7) + o) << 10) + hw] = res + bias[o];
    }
  }
}

// ---------------- host ----------------
extern "C" void kernel_launch(void* const* d_in, const int* in_sizes, int n_in,
                              void* d_out, int out_size, void* d_ws, size_t ws_size,
                              hipStream_t stream){
  const float* x    = (const float*)d_in[0];
  const float* wt   = (const float*)d_in[1];
  const float* bias = (const float*)d_in[2];
  float* out = (float*)d_out;
  char* ws = (char*)d_ws;
  uint32_t* hdr    = (uint32_t*)(ws + OFF_HDR);
  float*    wscale = (float*)(ws + OFF_WSCALE);
  int8_t*   wq     = (int8_t*)(ws + OFF_WQ);
  uint8_t*  cls    = (uint8_t*)(ws + OFF_CLS);
  uint8_t*  iq     = (uint8_t*)(ws + OFF_INPUTQ);
  uint32_t* packB  = (uint32_t*)(ws + OFF_PACKB);
  float*    rq     = (float*)(ws + OFF_RQ);
  float*    partial= (float*)(ws + OFF_PARTIAL);
  float*    outD   = (float*)(ws + OFF_OUTD);
  float*    outacc = (float*)(ws + OFF_OUTACC);

  // jax.random.key(42) -> (0,42); partitionable (fold-like) split:
  // kmask = threefry(key,(0,0)); knoise = threefry(key,(0,1))
  U2 p0 = threefry(0u, 42u, 0u, 0u);
  U2 p1 = threefry(0u, 42u, 0u, 1u);
  uint32_t km0 = p0.x, km1 = p0.y, kn0 = p1.x, kn1 = p1.y;

  hipLaunchKernelGGL(k_init,   dim3(1),           dim3(64),  0, stream, hdr);
  hipLaunchKernelGGL(k_xmax,   dim3(128),         dim3(256), 0, stream, x, hdr);
  hipLaunchKernelGGL(k_wq,     dim3(5, 128),      dim3(64),  0, stream, wt, wscale, wq);
  hipLaunchKernelGGL(k_inputq, dim3(8192),        dim3(256), 0, stream, x, hdr, iq);
  hipLaunchKernelGGL(k_pack,   dim3(640),         dim3(256), 0, stream, iq, packB);
  hipLaunchKernelGGL(k_cls,    dim3(NPTOT / 256), dim3(256), 0, stream, cls, km0, km1);
  hipLaunchKernelGGL(k_rq,     dim3(NNTOT / 256), dim3(256), 0, stream, wq, cls, rq, kn0, kn1);

  for (int z = 0; z < NZ; ++z){
    for (int k = 0; k < NK; ++k){
      int slot = z * NK + k;
      const float* rqsl = rq + (size_t)slot * NS * SUB * OC;
      const uint32_t* pbz = packB + (size_t)z * ROWS * 20;
      hipLaunchKernelGGL(k_mm,    dim3(128, 2, 5), dim3(256), 0, stream, rqsl, pbz, partial, hdr, slot);
      hipLaunchKernelGGL(k_quant, dim3(4096),      dim3(256), 0, stream, partial, wscale, hdr,
                         outD, outacc, out, bias, z, k, slot);
    }
  }
}

// Round 5
// 903.771 us; speedup vs baseline: 1.8602x; 1.7210x over previous
//
#include <hip/hip_runtime.h>
#include <stdint.h>

#define FPOFF _Pragma("clang fp contract(off)")

// ---------------- problem sizes ----------------
#define ROWS 8192      // N*Ho*Wo = 8*32*32
#define OC 128
#define NS 5           // subarrays
#define SUB 128
#define LP 640         // NS*SUB (padded L)
#define LREAL 576      // C*kh*kw = 64*9
#define NZ 7           // activation bits
#define NK 3           // weight cells
#define NSLOT 21
#define NPTOT 245760   // 3*128*5*128   probs element count
#define NNTOT 1720320  // 7*3*128*5*128 noise element count

// ---------------- ws layout (bytes) ----------------
#define OFF_HDR      0u          // u32[64]: [0]=xmax_enc, pmin[21]@idx8, pmax[21]@idx32
#define OFF_WSCALE   256u        // f32 [NS][OC]
#define OFF_WQ       4096u       // i8  [OC][LP]
#define OFF_CLS      86016u      // u8  [NK][OC][NS][SUB]
#define OFF_INPUTQ   331776u     // u8  [ROWS][LP]
#define OFF_PACKB    5574656u    // u32 [NZ][ROWS][NS][4]
#define OFF_RQ       10162176u   // f32 [NZ][NK][NS][SUB][OC]
#define OFF_PARTIAL  17043456u   // f32 [NS][ROWS][OC]
#define OFF_OUTD     38014976u   // f32 [ROWS][OC]
#define OFF_OUTACC   42209280u   // f32 [ROWS][OC]  (total ~46.4 MB)

struct U2 { uint32_t x, y; };

__host__ __device__ static inline uint32_t rotl32(uint32_t v, int d){ return (v << d) | (v >> (32 - d)); }

// JAX threefry2x32: 20 rounds, injection every 4. keys (k0,k1), counter (c0,c1).
__host__ __device__ static inline U2 threefry(uint32_t k0, uint32_t k1, uint32_t c0, uint32_t c1){
  uint32_t ks2 = k0 ^ k1 ^ 0x1BD11BDAu;
  uint32_t x0 = c0 + k0, x1 = c1 + k1;
#define TFR(r) { x0 += x1; x1 = rotl32(x1, r); x1 ^= x0; }
  TFR(13) TFR(15) TFR(26) TFR(6)  x0 += k1;  x1 += ks2 + 1u;
  TFR(17) TFR(29) TFR(16) TFR(24) x0 += ks2; x1 += k0 + 2u;
  TFR(13) TFR(15) TFR(26) TFR(6)  x0 += k0;  x1 += k1 + 3u;
  TFR(17) TFR(29) TFR(16) TFR(24) x0 += k1;  x1 += ks2 + 4u;
  TFR(13) TFR(15) TFR(26) TFR(6)  x0 += ks2; x1 += k0 + 5u;
#undef TFR
  U2 r; r.x = x0; r.y = x1; return r;
}

__device__ static inline float u2f(uint32_t b){
  // JAX uniform [0,1): bitcast((bits>>9)|0x3f800000) - 1
  return __uint_as_float((b >> 9) | 0x3F800000u) - 1.0f;
}

// order-preserving float<->uint encode for atomic min/max
__device__ static inline uint32_t encf(float f){
  uint32_t u = __float_as_uint(f);
  return (u & 0x80000000u) ? ~u : (u | 0x80000000u);
}
__device__ static inline float decf(uint32_t e){
  return (e & 0x80000000u) ? __uint_as_float(e & 0x7FFFFFFFu) : __uint_as_float(~e);
}

// XLA/chlo erf_inv f32 (Giles). log1p/sqrt via f64 for correctly-rounded f32.
__device__ static inline float xla_erfinv(float x){
  FPOFF
  float m = x * x;
  float w = -(float)log1p((double)(-m));
  float p;
  if (w < 5.0f){
    w = w - 2.5f;
    p = 2.81022636e-08f;
    p = 3.43273939e-07f  + p * w;
    p = -3.5233877e-06f  + p * w;
    p = -4.39150654e-06f + p * w;
    p = 0.00021858087f   + p * w;
    p = -0.00125372503f  + p * w;
    p = -0.00417768164f  + p * w;
    p = 0.246640727f     + p * w;
    p = 1.50140941f      + p * w;
  } else {
    w = (float)sqrt((double)w) - 3.0f;
    p = -0.000200214257f;
    p = 0.000100950558f  + p * w;
    p = 0.00134934322f   + p * w;
    p = -0.00367342844f  + p * w;
    p = 0.00573950773f   + p * w;
    p = -0.0076224613f   + p * w;
    p = 0.00943887047f   + p * w;
    p = 1.00167406f      + p * w;
    p = 2.83297682f      + p * w;
  }
  return p * x;
}

// ---------------- kernels ----------------

__global__ void k_init(uint32_t* hdr){
  int t = threadIdx.x;
  if (t == 0) hdr[0] = 0u;
  if (t < NSLOT){ hdr[8 + t] = 0xFFFFFFFFu; hdr[32 + t] = 0u; }
}

// two-stage max: per-thread 16 elems -> wave shuffle -> LDS -> 1 atomic/block
__global__ void k_xmax(const float* __restrict__ x, uint32_t* hdr){
  __shared__ float red[4];
  int t = threadIdx.x;
  const float4* x4 = (const float4*)x;
  int base = blockIdx.x * 1024 + t;     // 128 blocks * 1024 float4 = 524288 floats
  float m = 0.0f;                        // x >= 0 (uniform[0,1))
#pragma unroll
  for (int i = 0; i < 4; ++i){
    float4 v = x4[base + i * 256];
    m = fmaxf(m, fmaxf(fmaxf(v.x, v.y), fmaxf(v.z, v.w)));
  }
  for (int off = 32; off; off >>= 1) m = fmaxf(m, __shfl_down(m, off));
  if ((t & 63) == 0) red[t >> 6] = m;
  __syncthreads();
  if (t == 0){
    m = fmaxf(fmaxf(red[0], red[1]), fmaxf(red[2], red[3]));
    atomicMax(&hdr[0], encf(m));
  }
}

// per (s,o): w_scale = max(|w|,1e-8)/127 ; wq = rint(w/w_scale) as i8
__global__ void k_wq(const float* __restrict__ wt, float* __restrict__ wscale, int8_t* __restrict__ wq){
  FPOFF
  int s = blockIdx.x, o = blockIdx.y, t = threadIdx.x;  // 64 threads
  int l0 = s * SUB + t, l1 = l0 + 64;
  float w0 = (l0 < LREAL) ? wt[o * LREAL + l0] : 0.f;
  float w1 = (l1 < LREAL) ? wt[o * LREAL + l1] : 0.f;
  float m = fmaxf(fabsf(w0), fabsf(w1));
  for (int off = 32; off; off >>= 1) m = fmaxf(m, __shfl_down(m, off));
  m = __shfl(m, 0);
  float ws = fmaxf(m, 1e-8f) / 127.0f;
  if (t == 0) wscale[s * OC + o] = ws;
  wq[o * LP + l0] = (int8_t)(int)rintf(w0 / ws);
  wq[o * LP + l1] = (int8_t)(int)rintf(w1 / ws);
}

// im2col + per-tensor activation quant to u8
__global__ void k_inputq(const float* __restrict__ x, const uint32_t* __restrict__ hdr, uint8_t* __restrict__ iq){
  FPOFF
  int r = blockIdx.x, t = threadIdx.x;
  float a_scale = fmaxf(decf(hdr[0]), 1e-8f) / 127.0f;
  int n = r >> 10, hw = r & 1023, oh = hw >> 5, ow = hw & 31;
  for (int l = t; l < LP; l += 256){
    float val = 0.f;
    if (l < LREAL){
      int c = l / 9, r9 = l - c * 9, ki = r9 / 3, kj = r9 - ki * 3;
      int ih = oh - 1 + ki, iw = ow - 1 + kj;
      if ((unsigned)ih < 32u && (unsigned)iw < 32u)
        val = x[(((n << 6) + c) << 10) + (ih << 5) + iw];
    }
    iq[r * LP + l] = (uint8_t)(int)rintf(val / a_scale);
  }
}

// pack bit z of inputQ into u32 words: packB[z][r][s][w], bit t = j = w*32+t
__global__ void k_pack(const uint8_t* __restrict__ iq, uint32_t* __restrict__ packB){
  int gid = blockIdx.x * 256 + threadIdx.x;
  if (gid >= ROWS * 20) return;
  int r = gid / 20, sw = gid - r * 20;
  const uint4* p4 = (const uint4*)(iq + r * LP + sw * 32);
  uint4 a = p4[0], b2 = p4[1];
  uint32_t wds[8] = {a.x, a.y, a.z, a.w, b2.x, b2.y, b2.z, b2.w};
  uint32_t out[NZ];
#pragma unroll
  for (int z = 0; z < NZ; ++z) out[z] = 0u;
#pragma unroll
  for (int tt = 0; tt < 32; ++tt){
    uint32_t byte = (wds[tt >> 2] >> ((tt & 3) * 8)) & 0xFFu;
#pragma unroll
    for (int z = 0; z < NZ; ++z) out[z] |= ((byte >> z) & 1u) << tt;
  }
#pragma unroll
  for (int z = 0; z < NZ; ++z) packB[(z * ROWS + r) * 20 + sw] = out[z];
}

// SAF classes from uniform(kmask): 0 normal / 1 sa0 / 2 sa1
__global__ void k_cls(uint8_t* __restrict__ cls, uint32_t km0, uint32_t km1){
  int i = blockIdx.x * 256 + threadIdx.x;
  if (i >= NPTOT) return;
  U2 r = threefry(km0, km1, 0u, (uint32_t)i);
  float f = u2f(r.x ^ r.y);
  cls[i] = (f < 0.001f) ? 1 : ((f > 0.999f) ? 2 : 0);
}

// rQ[z][k][s][j][o] = SAF(where(sa)) of rem*(1+noise) — EXACT round-0 layout
__global__ void k_rq(const int8_t* __restrict__ wq, const uint8_t* __restrict__ cls,
                     float* __restrict__ rq, uint32_t kn0, uint32_t kn1){
  FPOFF
  int i = blockIdx.x * 256 + threadIdx.x;
  if (i >= NNTOT) return;
  U2 rr = threefry(kn0, kn1, 0u, (uint32_t)i);
  uint32_t bits = rr.x ^ rr.y;
  // noise flat index [z][k][o][s][j]
  int j = i & 127;
  int t = i >> 7;
  int s = t % 5;
  int t2 = t / 5;
  int o = t2 & 127;
  int t3 = t2 >> 7;
  int k = t3 % 3;
  int z = t3 / 3;
  float f = u2f(bits);
  float u = fmaxf(-0x1.fffffep-1f, f * 2.0f + (-0x1.fffffep-1f));
  float nv = (0x1.6a09e6p+0f * xla_erfinv(u)) * 0.05f;
  int wv = (int)wq[o * LP + s * SUB + j];
  int r0 = wv % 4;  int x1 = (wv - r0) / 4;
  int r1 = x1 % 4;  int x2 = (x1 - r1) / 4;
  int r2 = x2 % 4;
  int rem = (k == 0) ? r0 : ((k == 1) ? r1 : r2);
  float remf = (float)rem;
  float v = remf + remf * nv;
  int c = cls[((k * OC + o) * NS + s) * SUB + j];
  if (c == 1) v = 0.1f;
  else if (c == 2) v = (v > 0.f) ? 1.f : ((v < 0.f) ? -1.f : 0.f);
  rq[(((z * NK + k) * NS + s) * SUB + j) * OC + o] = v;
}

// partial[s][r][o] = sum_j bit(r,j) * rQ[j][o], j=0..127 strictly ascending.
// Round-0 mapping (lane = row, wave = 16-o tile) but the rq o-tile is fed
// from LDS via wave-uniform broadcast ds_read_b128 (4/j) instead of s_loads:
// the 32 KB (s, o-half) slice is staged once per block in the prologue.
// Inner issue per j: 16 v_fmac (v_acc, v_rq, v_bitf) + 2 bit VALU + 4 ds
// ~= 40 cyc for 1024 MACs.  FP chain order identical to round 0 (bit-exact).
__global__ __launch_bounds__(256) void k_mm(const float* __restrict__ rq_slice,
                                            const uint32_t* __restrict__ packB_z,
                                            float* __restrict__ partial,
                                            uint32_t* __restrict__ hdr, int slot){
  FPOFF
  __shared__ float lrq[128 * 64];   // [j][o_half]  32 KB
  __shared__ float red[8];
  const int tid  = threadIdx.x;
  const int wave = tid >> 6;
  const int lane = tid & 63;
  const int s    = blockIdx.z;
  const int r    = blockIdx.x * 64 + lane;
  const int o0   = blockIdx.y * 64 + wave * 16;

  // ---- stage rq[s][*][o-half] -> LDS (8192 floats, 8 float4/thread) ----
  {
    const float* gsrc = rq_slice + (size_t)s * SUB * OC + blockIdx.y * 64;
    const int jt = tid >> 4;          // 0..15
    const int ot = (tid & 15) * 4;    // 0,4,..,60
#pragma unroll
    for (int it = 0; it < 8; ++it){
      const int j = it * 16 + jt;
      const float4 v = *(const float4*)(gsrc + (size_t)j * OC + ot);
      *(float4*)&lrq[j * 64 + ot] = v;
    }
  }

  // per-lane bit words: packB row stride 80 B, s*16 B -> 16B-aligned uint4
  const uint4 bw4 = *(const uint4*)(packB_z + (size_t)r * 20 + s * 4);
  const uint32_t bwarr[4] = {bw4.x, bw4.y, bw4.z, bw4.w};

  __syncthreads();

  float acc[16];
#pragma unroll
  for (int i = 0; i < 16; ++i) acc[i] = 0.f;

#pragma unroll
  for (int w = 0; w < 4; ++w){
    const uint32_t bw = bwarr[w];
#pragma unroll
    for (int jj = 0; jj < 32; ++jj){
      const int msk = ((int)(bw << (31 - jj))) >> 31;             // v_bfe-style
      const float bitf = __uint_as_float((uint32_t)msk & 0x3F800000u);
      const float* lp = &lrq[(w * 32 + jj) * 64 + wave * 16];     // uniform -> ds broadcast
#pragma unroll
      for (int i = 0; i < 16; ++i)
        acc[i] = __builtin_fmaf(lp[i], bitf, acc[i]);             // j-ascending chain
    }
  }

  // store 16 consecutive o per lane (4x float4, 64B contiguous per lane)
  float4* pst = (float4*)(partial + (size_t)(s * ROWS + r) * OC + o0);
  pst[0] = make_float4(acc[0], acc[1], acc[2], acc[3]);
  pst[1] = make_float4(acc[4], acc[5], acc[6], acc[7]);
  pst[2] = make_float4(acc[8], acc[9], acc[10], acc[11]);
  pst[3] = make_float4(acc[12], acc[13], acc[14], acc[15]);

  float mn = acc[0], mx = acc[0];
#pragma unroll
  for (int i = 1; i < 16; ++i){ mn = fminf(mn, acc[i]); mx = fmaxf(mx, acc[i]); }
  for (int off = 32; off; off >>= 1){
    mn = fminf(mn, __shfl_down(mn, off));
    mx = fmaxf(mx, __shfl_down(mx, off));
  }
  if (lane == 0){ red[wave] = mn; red[4 + wave] = mx; }
  __syncthreads();
  if (tid == 0){
    mn = fminf(fminf(red[0], red[1]), fminf(red[2], red[3]));
    mx = fmaxf(fmaxf(red[4], red[5]), fmaxf(red[6], red[7]));
    atomicMin(&hdr[8 + slot], encf(mn));
    atomicMax(&hdr[32 + slot], encf(mx));
  }
}

// ADC quant + ws_T scale + subarray sum + z/k accumulation (reference order)
__global__ void k_quant(const float* __restrict__ partial, const float* __restrict__ wscale,
                        const uint32_t* __restrict__ hdr, float* __restrict__ outD,
                        float* __restrict__ outacc, float* __restrict__ out,
                        const float* __restrict__ bias, int z, int k, int slot){
  FPOFF
  int e = blockIdx.x * 256 + threadIdx.x;   // exactly ROWS*OC threads
  int r = e >> 7, o = e & 127;
  float mn = decf(hdr[8 + slot]);
  float mx = decf(hdr[32 + slot]);
  float delta = mx - mn;
  float step = delta * 0.03125f;
  if (!(step > 0.f)) step = 1.0f;
  float pq = 0.f;
#pragma unroll
  for (int s = 0; s < NS; ++s){
    float v = partial[(size_t)(s * ROWS + r) * OC + o];
    float fidx = floorf((v - mn) / step);
    fidx = fminf(fmaxf(fidx, 0.f), 31.f);
    float qv = fidx * step + mn;
    pq = pq + qv * wscale[s * OC + o];
  }
  if (k == 0) outD[e] = pq;
  else if (k == 1) outD[e] = outD[e] + pq * 4.0f;
  else {
    float tt = outD[e] + pq * 16.0f;
    float a_scale = fmaxf(decf(hdr[0]), 1e-8f) / 127.0f;
    float contrib = (tt * (float)(1 << z)) * a_scale;
    if (z == 0) outacc[e] = contrib;
    else if (z < 6) outacc[e] = outacc[e] + contrib;
    else {
      float res = outacc[e] + contrib;
      int n = r >> 10, hw = r & 1023;
      out[(((n << 7) + o) << 10) + hw] = res + bias[o];
    }
  }
}

// ---------------- host ----------------
extern "C" void kernel_launch(void* const* d_in, const int* in_sizes, int n_in,
                              void* d_out, int out_size, void* d_ws, size_t ws_size,
                              hipStream_t stream){
  const float* x    = (const float*)d_in[0];
  const float* wt   = (const float*)d_in[1];
  const float* bias = (const float*)d_in[2];
  float* out = (float*)d_out;
  char* ws = (char*)d_ws;
  uint32_t* hdr    = (uint32_t*)(ws + OFF_HDR);
  float*    wscale = (float*)(ws + OFF_WSCALE);
  int8_t*   wq     = (int8_t*)(ws + OFF_WQ);
  uint8_t*  cls    = (uint8_t*)(ws + OFF_CLS);
  uint8_t*  iq     = (uint8_t*)(ws + OFF_INPUTQ);
  uint32_t* packB  = (uint32_t*)(ws + OFF_PACKB);
  float*    rq     = (float*)(ws + OFF_RQ);
  float*    partial= (float*)(ws + OFF_PARTIAL);
  float*    outD   = (float*)(ws + OFF_OUTD);
  float*    outacc = (float*)(ws + OFF_OUTACC);

  // jax.random.key(42) -> (0,42); partitionable (fold-like) split:
  // kmask = threefry(key,(0,0)); knoise = threefry(key,(0,1))
  U2 p0 = threefry(0u, 42u, 0u, 0u);
  U2 p1 = threefry(0u, 42u, 0u, 1u);
  uint32_t km0 = p0.x, km1 = p0.y, kn0 = p1.x, kn1 = p1.y;

  hipLaunchKernelGGL(k_init,   dim3(1),           dim3(64),  0, stream, hdr);
  hipLaunchKernelGGL(k_xmax,   dim3(128),         dim3(256), 0, stream, x, hdr);
  hipLaunchKernelGGL(k_wq,     dim3(5, 128),      dim3(64),  0, stream, wt, wscale, wq);
  hipLaunchKernelGGL(k_inputq, dim3(8192),        dim3(256), 0, stream, x, hdr, iq);
  hipLaunchKernelGGL(k_pack,   dim3(640),         dim3(256), 0, stream, iq, packB);
  hipLaunchKernelGGL(k_cls,    dim3(NPTOT / 256), dim3(256), 0, stream, cls, km0, km1);
  hipLaunchKernelGGL(k_rq,     dim3(NNTOT / 256), dim3(256), 0, stream, wq, cls, rq, kn0, kn1);

  for (int z = 0; z < NZ; ++z){
    for (int k = 0; k < NK; ++k){
      int slot = z * NK + k;
      const float* rqsl = rq + (size_t)slot * NS * SUB * OC;
      const uint32_t* pbz = packB + (size_t)z * ROWS * 20;
      hipLaunchKernelGGL(k_mm,    dim3(128, 2, 5), dim3(256), 0, stream, rqsl, pbz, partial, hdr, slot);
      hipLaunchKernelGGL(k_quant, dim3(4096),      dim3(256), 0, stream, partial, wscale, hdr,
                         outD, outacc, out, bias, z, k, slot);
    }
  }
}